// Round 5
// baseline (115.322 us; speedup 1.0000x reference)
//
#include <hip/hip_runtime.h>

// Edgenet: 4-channel fixed 3x3 Sobel-family stencil on [64,1,512,512] f32,
// edge = (sum_c |conv_c|) > 0 ? 1 : 0, output int32 [64,512,512].
//
// Round-5: round-4 retry with a compile fix. Wave-owns-512px-strip sliding
// window, R_ROWS=4 (8192 waves = 8 waves/SIMD for latency hiding), and
// nontemporal int stores via a native clang ext_vector_type(4) (the HIP
// int4 wrapper type is rejected by __builtin_nontemporal_store).
// __launch_bounds__(256,8) caps VGPR at 64 so all 8 waves/SIMD are resident.

#define IMG_W 512
#define IMG_H 512
#define R_ROWS 4

typedef int iv4 __attribute__((ext_vector_type(4)));

struct Row {
  float4 lo, hi;   // pixels 8l..8l+3, 8l+4..8l+7
  float lft, rgt;  // halo pixels 8l-1, 8l+8
};

__device__ __forceinline__ float rget(const Row& r, int k) {
  switch (k) {   // k is compile-time constant after full unroll
    case 0: return r.lft;
    case 1: return r.lo.x; case 2: return r.lo.y;
    case 3: return r.lo.z; case 4: return r.lo.w;
    case 5: return r.hi.x; case 6: return r.hi.y;
    case 7: return r.hi.z; case 8: return r.hi.w;
    default: return r.rgt;
  }
}

__device__ __forceinline__ void loadrow(Row& r, const float* img, int yy, int px) {
  if ((unsigned)yy < (unsigned)IMG_H) {   // wave-uniform branch
    const float* p = img + yy * IMG_W + px;
    r.lo = *reinterpret_cast<const float4*>(p);
    r.hi = *reinterpret_cast<const float4*>(p + 4);
  } else {
    r.lo = make_float4(0.f, 0.f, 0.f, 0.f);
    r.hi = make_float4(0.f, 0.f, 0.f, 0.f);
  }
}

__device__ __forceinline__ void finishrow(Row& r, int lane) {
  // vmcnt wait lands here at first use of loaded data
  float lf = __shfl_up(r.hi.w, 1);
  float rt = __shfl_down(r.lo.x, 1);
  r.lft = (lane == 0)  ? 0.f : lf;   // pixel -1  -> 0 (image edge)
  r.rgt = (lane == 63) ? 0.f : rt;   // pixel 512 -> 0
}

__device__ __forceinline__ void compute_store(const Row& T, const Row& M,
                                              const Row& B, int* orow) {
  int res[8];
#pragma unroll
  for (int j = 0; j < 8; ++j) {
    float t0 = rget(T, j), t1 = rget(T, j + 1), t2 = rget(T, j + 2);
    float m0 = rget(M, j),                      m2 = rget(M, j + 2);
    float b0 = rget(B, j), b1 = rget(B, j + 1), b2 = rget(B, j + 2);
    float tx = (b0 - t0) + 2.f * (b1 - t1) + (b2 - t2);            // f_x
    float ty = (t2 - t0) + 2.f * (m2 - m0) + (b2 - b0);            // f_y
    float d1 = -2.f * t0 - t1 - m0 + m2 + b1 + 2.f * b2;           // f_tl_br
    float d2 = -t1 - 2.f * t2 + m0 - m2 + 2.f * b0 + b1;           // f_tr_bl
    float e = fabsf(tx) + fabsf(ty) + fabsf(d1) + fabsf(d2);
    res[j] = (e > 0.f) ? 1 : 0;
  }
  iv4 a = {res[0], res[1], res[2], res[3]};
  iv4 b4 = {res[4], res[5], res[6], res[7]};
  __builtin_nontemporal_store(a,  reinterpret_cast<iv4*>(orow));
  __builtin_nontemporal_store(b4, reinterpret_cast<iv4*>(orow + 4));
}

__global__ __launch_bounds__(256, 8) void edgenet_kernel(
    const float* __restrict__ in, int* __restrict__ out) {
  const int lane = threadIdx.x & 63;
  const int wid  = threadIdx.x >> 6;                       // 0..3
  const int b    = blockIdx.x >> 5;                        // image index
  const int y0   = ((blockIdx.x & 31) << 4) + (wid << 2);  // strip start row
  const int px   = lane << 3;                              // first pixel of lane

  const float* img = in + (size_t)b * (IMG_H * IMG_W);
  int* orow = out + ((size_t)b * IMG_H + y0) * IMG_W + px;

  Row s[4];
  // prologue: rows y0-1 .. y0+2 in flight
  loadrow(s[0], img, y0 - 1, px);
  loadrow(s[1], img, y0,     px);
  loadrow(s[2], img, y0 + 1, px);
  loadrow(s[3], img, y0 + 2, px);
  finishrow(s[0], lane);
  finishrow(s[1], lane);

#pragma unroll
  for (int i = 0; i < R_ROWS; ++i) {
    finishrow(s[(i + 2) & 3], lane);                 // row y0+i+1 ready
    compute_store(s[i & 3], s[(i + 1) & 3], s[(i + 2) & 3],
                  orow + i * IMG_W);
    if (i < R_ROWS - 2)                              // rows y0+3, y0+4
      loadrow(s[i & 3], img, y0 + i + 3, px);        // slot y0+i-1 is dead
  }
}

extern "C" void kernel_launch(void* const* d_in, const int* in_sizes, int n_in,
                              void* d_out, int out_size, void* d_ws, size_t ws_size,
                              hipStream_t stream) {
  const float* lab = (const float*)d_in[0];
  int* out = (int*)d_out;
  // 64 images x 32 blocks per image (block: 4 waves x 4-row strips = 16 rows)
  int blocks = 64 * (IMG_H / (4 * R_ROWS));          // 2048
  edgenet_kernel<<<blocks, 256, 0, stream>>>(lab, out);
}

// Round 6
// 28.819 us; speedup vs baseline: 4.0015x; 4.0015x over previous
//
#include <hip/hip_runtime.h>

// Edgenet: 4-channel fixed 3x3 Sobel-family stencil on [64,1,512,512] f32,
// edge = (sum_c |conv_c|) > 0 ? 1 : 0, output int32 [64,512,512].
//
// Round-6: revert round-4/5 regressions (NO nontemporal stores -- they 5x'd
// WRITE_SIZE; back to R=8 vertical ratio whose FETCH was near-ideal 65 MiB).
// New lever: horizontal strip split. Each wave owns a 256px x 8row strip
// (lane <-> 4 px, one float4 per row), doubling waves to 8192 = 8/SIMD for
// latency hiding. Strip-boundary halos: one 2-active-lane predicated scalar
// load per row. 4-slot register sliding window, loads 2 rows ahead.

#define IMG_W 512
#define IMG_H 512
#define R_ROWS 8

struct Row {
  float4 m;        // pixels px .. px+3
  float hx;        // raw halo value (meaningful in lanes 0 and 63 only)
  float lft, rgt;  // resolved halo pixels px-1, px+4
};

__device__ __forceinline__ float rget(const Row& r, int k) {
  switch (k) {   // k is compile-time constant after full unroll
    case 0: return r.lft;
    case 1: return r.m.x; case 2: return r.m.y;
    case 3: return r.m.z; case 4: return r.m.w;
    default: return r.rgt;
  }
}

__device__ __forceinline__ void loadrow(Row& r, const float* img, int yy,
                                        int px, int lane) {
  if ((unsigned)yy < (unsigned)IMG_H) {   // wave-uniform branch
    const float* row = img + yy * IMG_W;
    r.m = *reinterpret_cast<const float4*>(row + px);
    if (lane == 0 || lane == 63) {        // 2-lane predicated halo load
      int hidx = (lane == 0) ? px - 1 : px + 4;
      r.hx = ((unsigned)hidx < (unsigned)IMG_W) ? row[hidx] : 0.f;
    }
  } else {
    r.m = make_float4(0.f, 0.f, 0.f, 0.f);
    r.hx = 0.f;
  }
}

__device__ __forceinline__ void finishrow(Row& r, int lane) {
  // vmcnt wait lands here at first use of loaded data
  float lf = __shfl_up(r.m.w, 1);
  float rt = __shfl_down(r.m.x, 1);
  r.lft = (lane == 0)  ? r.hx : lf;   // hx==0 at true image edge
  r.rgt = (lane == 63) ? r.hx : rt;
}

__device__ __forceinline__ void compute_store(const Row& T, const Row& M,
                                              const Row& B, int* orow) {
  int res[4];
#pragma unroll
  for (int j = 0; j < 4; ++j) {
    float t0 = rget(T, j), t1 = rget(T, j + 1), t2 = rget(T, j + 2);
    float m0 = rget(M, j),                      m2 = rget(M, j + 2);
    float b0 = rget(B, j), b1 = rget(B, j + 1), b2 = rget(B, j + 2);
    float tx = (b0 - t0) + 2.f * (b1 - t1) + (b2 - t2);            // f_x
    float ty = (t2 - t0) + 2.f * (m2 - m0) + (b2 - b0);            // f_y
    float d1 = -2.f * t0 - t1 - m0 + m2 + b1 + 2.f * b2;           // f_tl_br
    float d2 = -t1 - 2.f * t2 + m0 - m2 + 2.f * b0 + b1;           // f_tr_bl
    float e = fabsf(tx) + fabsf(ty) + fabsf(d1) + fabsf(d2);
    res[j] = (e > 0.f) ? 1 : 0;
  }
  *reinterpret_cast<int4*>(orow) = make_int4(res[0], res[1], res[2], res[3]);
}

__global__ __launch_bounds__(256) void edgenet_kernel(
    const float* __restrict__ in, int* __restrict__ out) {
  const int lane = threadIdx.x & 63;
  const int wid  = threadIdx.x >> 6;                 // 0..3
  const int b    = blockIdx.x >> 5;                  // image index
  const int w    = ((blockIdx.x & 31) << 2) | wid;   // wave id in image, 0..127
  const int sx   = w & 1;                            // horizontal strip
  const int y0   = (w >> 1) << 3;                    // strip start row
  const int px   = (sx << 8) + (lane << 2);          // first pixel of lane

  const float* img = in + (size_t)b * (IMG_H * IMG_W);
  int* orow = out + ((size_t)b * IMG_H + y0) * IMG_W + px;

  Row s[4];
  // prologue: rows y0-1 .. y0+2 in flight
  loadrow(s[0], img, y0 - 1, px, lane);
  loadrow(s[1], img, y0,     px, lane);
  loadrow(s[2], img, y0 + 1, px, lane);
  loadrow(s[3], img, y0 + 2, px, lane);
  finishrow(s[0], lane);
  finishrow(s[1], lane);

#pragma unroll
  for (int i = 0; i < R_ROWS; ++i) {
    finishrow(s[(i + 2) & 3], lane);                 // row y0+i+1 ready
    compute_store(s[i & 3], s[(i + 1) & 3], s[(i + 2) & 3],
                  orow + i * IMG_W);
    if (i < R_ROWS - 2)                              // rows y0+3 .. y0+8
      loadrow(s[i & 3], img, y0 + i + 3, px, lane);  // slot y0+i-1 is dead
  }
}

extern "C" void kernel_launch(void* const* d_in, const int* in_sizes, int n_in,
                              void* d_out, int out_size, void* d_ws, size_t ws_size,
                              hipStream_t stream) {
  const float* lab = (const float*)d_in[0];
  int* out = (int*)d_out;
  // 64 images x 32 blocks (block: 4 waves; wave: 256px x 8row strip)
  int blocks = 64 * 32;                              // 2048
  edgenet_kernel<<<blocks, 256, 0, stream>>>(lab, out);
}